// Round 1
// baseline (720.444 us; speedup 1.0000x reference)
//
#include <hip/hip_runtime.h>
#include <math.h>

#define KS 48
#define TLEN 512
#define BN 1024
#define START_S 46
#define STOP_S 47
#define NEGV -10000.0f

__global__ __launch_bounds__(64) void crf_kernel(
    const float* __restrict__ feats,   // [B, T, K]
    const float* __restrict__ trans,   // [K, K]  (trans[next, prev])
    const int*   __restrict__ tags,    // [B, T]
    float*       __restrict__ out)     // [B] nll | [B] path_score | [B*T] paths
{
    const int b    = blockIdx.x;
    const int lane = threadIdx.x;
    const bool act = lane < KS;

    __shared__ float4 u4[KS / 4];                 // forward exp(alpha - m)
    __shared__ float4 w4[KS / 4];                 // viterbi values
    __shared__ unsigned char bp_sh[TLEN][KS];     // backpointers (24 KB)
    __shared__ unsigned char path_sh[TLEN];

    float* u_sh = (float*)u4;
    float* w_sh = (float*)w4;

    const float* fb = feats + (size_t)b * TLEN * KS;
    const int*   tb = tags + (size_t)b * TLEN;

    // ---- per-lane transition row (lane = next state), masked ----
    float Trow[KS];   // trans[next=lane][prev=p], masked
    float Erow[KS];   // exp(Trow)
    {
        const float* tr = trans + (act ? lane : 0) * KS;
        #pragma unroll
        for (int p = 0; p < KS; ++p) {
            float tv = act ? tr[p] : NEGV;
            if (lane == START_S) tv = NEGV;   // never INTO start
            if (p == STOP_S)     tv = NEGV;   // never OUT of stop
            Trow[p] = tv;
            Erow[p] = __expf(tv);             // exp(-10000) == 0 -> mask for free
        }
    }

    float alpha = (act && lane == START_S) ? 0.0f : -INFINITY;          // forward
    float vit   = (lane == START_S) ? 0.0f : (act ? NEGV : -3.0e38f);   // viterbi

    for (int t = 0; t < TLEN; ++t) {
        float emit = act ? fb[t * KS + lane] : 0.0f;

        // wave max of alpha (m is finite: at least one finite state always)
        float m = alpha;
        #pragma unroll
        for (int off = 32; off; off >>= 1)
            m = fmaxf(m, __shfl_xor(m, off, 64));

        float ue = __expf(alpha - m);   // -inf lanes -> 0

        if (act) { u_sh[lane] = ue; w_sh[lane] = vit; }
        __syncthreads();

        float acc  = 0.0f;
        float best = -3.0e38f;
        int   bp   = 0;
        #pragma unroll
        for (int p = 0; p < KS; p += 4) {
            float4 uu = u4[p / 4];
            float4 vv = w4[p / 4];
            acc = fmaf(uu.x, Erow[p + 0], acc);
            acc = fmaf(uu.y, Erow[p + 1], acc);
            acc = fmaf(uu.z, Erow[p + 2], acc);
            acc = fmaf(uu.w, Erow[p + 3], acc);
            // viterbi: exact same add as reference; strict > keeps first-index max
            float s0 = vv.x + Trow[p + 0]; if (s0 > best) { best = s0; bp = p + 0; }
            float s1 = vv.y + Trow[p + 1]; if (s1 > best) { best = s1; bp = p + 1; }
            float s2 = vv.z + Trow[p + 2]; if (s2 > best) { best = s2; bp = p + 2; }
            float s3 = vv.w + Trow[p + 3]; if (s3 > best) { best = s3; bp = p + 3; }
        }
        __syncthreads();   // WAR: next iter rewrites u_sh/w_sh

        alpha = emit + m + __logf(acc);   // acc==0 (next==START) -> -inf, harmless
        vit   = best + emit;
        if (act) bp_sh[t][lane] = (unsigned char)bp;
    }

    // ---- terminal transition row trans[STOP, prev=lane], masked ----
    float tstop = act ? trans[STOP_S * KS + lane] : NEGV;
    if (lane == STOP_S) tstop = NEGV;

    // ---- logZ = LSE(alpha + trans[STOP]) ----
    float z = alpha + tstop;   // -inf lanes stay -inf
    float mz = z;
    #pragma unroll
    for (int off = 32; off; off >>= 1)
        mz = fmaxf(mz, __shfl_xor(mz, off, 64));
    float se = __expf(z - mz);
    #pragma unroll
    for (int off = 32; off; off >>= 1)
        se += __shfl_xor(se, off, 64);
    float logZ = mz + __logf(se);

    // ---- viterbi terminal: argmax(term), first-index tie-break ----
    float term = act ? (vit + tstop) : -3.0e38f;
    float bv = term;
    int   bi = act ? lane : 9999;
    #pragma unroll
    for (int off = 32; off; off >>= 1) {
        float ov = __shfl_xor(bv, off, 64);
        int   oi = __shfl_xor(bi, off, 64);
        if (ov > bv || (ov == bv && oi < bi)) { bv = ov; bi = oi; }
    }
    float path_score = bv;
    int   best_last  = bi;

    // ---- gold score (all 64 lanes, 8 timesteps each) ----
    float g = 0.0f;
    for (int t = lane; t < TLEN; t += 64) {
        int tg = tb[t];
        int pg = (t == 0) ? START_S : tb[t - 1];
        // masked trans == raw trans at these entries (tg < 46, pg != 47)
        g += fb[t * KS + tg] + trans[tg * KS + pg];
    }
    #pragma unroll
    for (int off = 32; off; off >>= 1)
        g += __shfl_xor(g, off, 64);
    g += trans[STOP_S * KS + tb[TLEN - 1]];

    if (lane == 0) {
        out[b]      = logZ - g;      // nll
        out[BN + b] = path_score;
    }

    // ---- backtrace (uniform across wave; broadcast LDS reads) ----
    int tag = best_last;
    for (int t = TLEN - 1; t >= 0; --t) {
        if (lane == 0) path_sh[t] = (unsigned char)tag;
        tag = bp_sh[t][tag];
    }
    __syncthreads();

    float* pout = out + 2 * BN + (size_t)b * TLEN;
    for (int t = lane; t < TLEN; t += 64)
        pout[t] = (float)path_sh[t];
}

extern "C" void kernel_launch(void* const* d_in, const int* in_sizes, int n_in,
                              void* d_out, int out_size, void* d_ws, size_t ws_size,
                              hipStream_t stream) {
    const float* feats = (const float*)d_in[0];
    const float* trans = (const float*)d_in[1];
    const int*   tags  = (const int*)d_in[2];
    float*       out   = (float*)d_out;
    (void)in_sizes; (void)n_in; (void)out_size; (void)d_ws; (void)ws_size;
    crf_kernel<<<dim3(BN), dim3(64), 0, stream>>>(feats, trans, tags, out);
}